// Round 6
// baseline (1504.169 us; speedup 1.0000x reference)
//
#include <hip/hip_runtime.h>
#include <hip/hip_bf16.h>

#define HID 128
#define SEQ 512
#define INS 14
#define BC 16
// K0 = 160 : [x(14) | 1 | pad->32 | h0(128)]   -> 5 k-steps of 32
// K1 = 256 : [h0(128) | h1(128)]               -> 8 k-steps of 32
#define X0STRIDE 40
#define X1STRIDE 264  // 256 + 8 pad shorts
#define NFRAG0 10240          // 8 unit-groups * 4 gates * 5 ksteps * 64 lanes
#define NFRAG1 16384          // 8 unit-groups * 4 gates * 8 ksteps * 64 lanes
#define W1BASE (NFRAG0 * 8)   // short offset of W1 region in ws

typedef __attribute__((ext_vector_type(8))) short bs8;
typedef __attribute__((ext_vector_type(4))) float f4;

__device__ __forceinline__ short f2bf(float f) {
    union { float f; unsigned u; } a; a.f = f;
    unsigned u = a.u;
    u += 0x7fffu + ((u >> 16) & 1u);   // RNE
    return (short)(u >> 16);
}
__device__ __forceinline__ float bf2f(short s) {
    union { unsigned u; float f; } a;
    a.u = ((unsigned)(unsigned short)s) << 16;
    return a.f;
}
__device__ __forceinline__ float sigm(float x) {
    return __builtin_amdgcn_rcpf(1.f + __builtin_amdgcn_exp2f(x * -1.44269504f));
}

// ---------------------------------------------------------------------------
// prep: swizzle weights into MFMA B-fragment order in ws (bf16 bits).
// (unchanged layout; main kernel reads role-dependent subsets)
// ---------------------------------------------------------------------------
__global__ void lstm_prep(
    const float* __restrict__ Wih0, const float* __restrict__ Whh0,
    const float* __restrict__ bih0, const float* __restrict__ bhh0,
    const float* __restrict__ Wih1, const float* __restrict__ Whh1,
    short* __restrict__ wsw)
{
    int f = blockIdx.x * 256 + threadIdx.x;
    if (f >= NFRAG0 + NFRAG1) return;
    if (f < NFRAG0) {
        int lane = f & 63, t = f >> 6;
        int ks = t % 5, gw = t / 5, g = gw & 3, wv = gw >> 2;
        int row = g * HID + wv * 16 + (lane & 15);
        int kbase = ks * 32 + (lane >> 4) * 8;
        for (int j = 0; j < 8; ++j) {
            int k = kbase + j;
            float v;
            if (k < INS)        v = Wih0[row * INS + k];
            else if (k == INS)  v = bih0[row] + bhh0[row];
            else if (k < 32)    v = 0.f;
            else                v = Whh0[row * HID + (k - 32)];
            wsw[f * 8 + j] = f2bf(v);
        }
    } else {
        int fl = f - NFRAG0;
        int lane = fl & 63, t = fl >> 6;
        int ks = t & 7, g = (t >> 3) & 3, wv = t >> 5;
        int row = g * HID + wv * 16 + (lane & 15);
        int kbase = ks * 32 + (lane >> 4) * 8;
        for (int j = 0; j < 8; ++j) {
            int k = kbase + j;
            float v = (k < HID) ? Wih1[row * HID + k] : Whh1[row * HID + (k - HID)];
            wsw[f * 8 + j] = f2bf(v);
        }
    }
}

// ---------------------------------------------------------------------------
// main. Round-6: WAVE ROLE-SPECIALIZATION, 16 waves (1024 thr), 4 waves/SIMD.
// Waves 0-7 = L0-only (unit group wv), waves 8-15 = L1-only (unit group
// wv-8). L0(t) and L1(t-1) have no intra-step dependency (1-step pipeline,
// r1): both read parity-p, write disjoint parity-q regions -> single uniform
// barrier per step, role branch contains no barrier. Per-wave work halves;
// per-SIMD issue unchanged; 4 waves/SIMD hide the latency that 2 could not
// (r5 evidence: re-ordering 2 lockstep waves regressed -> stall is latency,
// not order). Unified frag slots (5/gate, regs): L0 ks0-4, L1 ks0-4; L1
// ks5-7 live in wlds (96 KB). LDS 118 KB. Hard 128-VGPR cap at 4 waves/SIMD
// -> spill canary: WRITE_SIZE (~8 KB @ r4; MBs = spilled).
// ---------------------------------------------------------------------------
__global__ __attribute__((amdgpu_flat_work_group_size(1024, 1024)))
__attribute__((amdgpu_waves_per_eu(4, 4))) void lstm_fused(
    const float* __restrict__ x,
    const float* __restrict__ Wfc,  const float* __restrict__ bfc,
    const float* __restrict__ bih1, const float* __restrict__ bhh1,
    const short* __restrict__ wsw,
    float* __restrict__ out)
{
    __shared__ __align__(16) short xh0[2][BC][X0STRIDE];
    __shared__ __align__(16) short xh1[2][BC][X1STRIDE];
    // L1 ks5-7 weights: [unit-group][ks-5][gate][lane][8] -> 96 KB
    __shared__ __align__(16) short wlds[8][3][4][64][8];

    const int tid  = threadIdx.x;
    const int lane = tid & 63;
    const int wv   = tid >> 6;          // 0..15
    const int col  = lane & 15;
    const int quad = lane >> 4;
    const bool isL1 = (wv >= 8);
    const int uw   = isL1 ? (wv - 8) : wv;  // unit group 0..7
    const int u    = uw * 16 + col;         // hidden unit owned by this lane
    const int b0   = blockIdx.x * BC;

    // ---- role-dependent register frags: 20 per wave (5 slots x 4 gates) ----
    const short* wb = isL1 ? (wsw + W1BASE + ((uw * 32) * 64 + lane) * 8)
                           : (wsw + ((uw * 20) * 64 + lane) * 8);
#define DWJ(g,j) const bs8 w_##g##_##j = *(const bs8*)(wb + (isL1 ? ((g)*8+(j)) : ((g)*5+(j)))*512);
    DWJ(0,0) DWJ(0,1) DWJ(0,2) DWJ(0,3) DWJ(0,4)
    DWJ(1,0) DWJ(1,1) DWJ(1,2) DWJ(1,3) DWJ(1,4)
    DWJ(2,0) DWJ(2,1) DWJ(2,2) DWJ(2,3) DWJ(2,4)
    DWJ(3,0) DWJ(3,1) DWJ(3,2) DWJ(3,3) DWJ(3,4)

    // b1 used only on the L1 path (4 regs, role-disjoint with L0's use)
    const float b1_0 = bih1[0 * HID + u] + bhh1[0 * HID + u];
    const float b1_1 = bih1[1 * HID + u] + bhh1[1 * HID + u];
    const float b1_2 = bih1[2 * HID + u] + bhh1[2 * HID + u];
    const float b1_3 = bih1[3 * HID + u] + bhh1[3 * HID + u];

    // ---- LDS init: zeros + L1 ks5-7 weight tiles + constant-1 bias col ----
    for (int idx = tid; idx < 2 * BC * X0STRIDE; idx += 1024) ((short*)xh0)[idx] = 0;
    for (int idx = tid; idx < 2 * BC * X1STRIDE; idx += 1024) ((short*)xh1)[idx] = 0;
    if (isL1) {
#pragma unroll
        for (int f = 0; f < 12; ++f) {
            int m = f >> 2, g = f & 3;   // m: ks-5
            *(bs8*)&wlds[uw][m][g][lane][0] =
                *(const bs8*)(wsw + W1BASE +
                    (((uw * 4 + g) * 8 + (m + 5)) * 64 + lane) * 8);
        }
    }
    __syncthreads();
    if (tid < 2 * BC) xh0[tid >> 4][tid & 15][INS] = (short)0x3f80;  // 1.0 bf16

    // ---- x(t) staging: 224 loader threads (all in L0 waves 0-3) ----
    const bool xldr = (tid < BC * INS);
    const int  xm = tid / INS;
    const int  xi = tid - xm * INS;
    const float* xp = xldr ? (x + ((size_t)(b0 + xm) * SEQ) * INS + xi) : x;
    float xv = xldr ? xp[0] : 0.f;

    // cell state: L0 waves use as c0, L1 waves as c1 (roles disjoint)
    float c_0 = 0.f, c_1 = 0.f, c_2 = 0.f, c_3 = 0.f;
    const int aoff = quad * 8;

#define MFM(ACC, AF, W) ACC = __builtin_amdgcn_mfma_f32_16x16x32_bf16(AF, W, ACC, 0,0,0);

    // merged-denominator cell (r4 numerics, unchanged): 5 exp2 + 2 rcp / row
#define CELLW(A0, A1, A2, A3, r, COLOFF) { \
        float ei = __builtin_amdgcn_exp2f(A0[r] * -1.44269504f); \
        float ef = __builtin_amdgcn_exp2f(A1[r] * -1.44269504f); \
        float eg = __builtin_amdgcn_exp2f(A2[r] * -2.88539008f); \
        float eo = __builtin_amdgcn_exp2f(A3[r] * -1.44269504f); \
        float Di = 1.f + ei, Df = 1.f + ef, Dg = 1.f + eg, Do = 1.f + eo; \
        float rP = __builtin_amdgcn_rcpf(Df * Di * Dg); \
        float num = __builtin_fmaf(c_##r * Di, Dg, (1.f - eg) * Df); \
        c_##r = num * rP; \
        float ec = __builtin_amdgcn_exp2f(c_##r * -2.88539008f); \
        float rQ = __builtin_amdgcn_rcpf((1.f + ec) * Do); \
        float h = (1.f - ec) * rQ; \
        xh1[q][quad * 4 + (r)][(COLOFF) + u] = f2bf(h); }

#define L0BODY { \
        const bs8 afx = *(const bs8*)&xh0[p][col][aoff]; \
        const bs8 af0 = *(const bs8*)&xh1[p][col][0 * 32 + aoff]; \
        const bs8 af1 = *(const bs8*)&xh1[p][col][1 * 32 + aoff]; \
        const bs8 af2 = *(const bs8*)&xh1[p][col][2 * 32 + aoff]; \
        const bs8 af3 = *(const bs8*)&xh1[p][col][3 * 32 + aoff]; \
        f4 a0 = {0.f,0.f,0.f,0.f}, a1 = {0.f,0.f,0.f,0.f}; \
        f4 a2 = {0.f,0.f,0.f,0.f}, a3 = {0.f,0.f,0.f,0.f}; \
        MFM(a0, afx, w_0_0) MFM(a1, afx, w_1_0) MFM(a2, afx, w_2_0) MFM(a3, afx, w_3_0) \
        MFM(a0, af0, w_0_1) MFM(a1, af0, w_1_1) MFM(a2, af0, w_2_1) MFM(a3, af0, w_3_1) \
        MFM(a0, af1, w_0_2) MFM(a1, af1, w_1_2) MFM(a2, af1, w_2_2) MFM(a3, af1, w_3_2) \
        MFM(a0, af2, w_0_3) MFM(a1, af2, w_1_3) MFM(a2, af2, w_2_3) MFM(a3, af2, w_3_3) \
        MFM(a0, af3, w_0_4) MFM(a1, af3, w_1_4) MFM(a2, af3, w_2_4) MFM(a3, af3, w_3_4) \
        CELLW(a0, a1, a2, a3, 0, 0) CELLW(a0, a1, a2, a3, 1, 0) \
        CELLW(a0, a1, a2, a3, 2, 0) CELLW(a0, a1, a2, a3, 3, 0) }

#define L1WL(m, AF) { \
        const bs8 v0 = *(const bs8*)&wlds[uw][m][0][lane][0]; \
        const bs8 v1 = *(const bs8*)&wlds[uw][m][1][lane][0]; \
        const bs8 v2 = *(const bs8*)&wlds[uw][m][2][lane][0]; \
        const bs8 v3 = *(const bs8*)&wlds[uw][m][3][lane][0]; \
        MFM(a0, AF, v0) MFM(a1, AF, v1) MFM(a2, AF, v2) MFM(a3, AF, v3) }

#define L1BODY { \
        const bs8 af0 = *(const bs8*)&xh1[p][col][0 * 32 + aoff]; \
        const bs8 af1 = *(const bs8*)&xh1[p][col][1 * 32 + aoff]; \
        const bs8 af2 = *(const bs8*)&xh1[p][col][2 * 32 + aoff]; \
        const bs8 af3 = *(const bs8*)&xh1[p][col][3 * 32 + aoff]; \
        const bs8 af4 = *(const bs8*)&xh1[p][col][4 * 32 + aoff]; \
        const bs8 af5 = *(const bs8*)&xh1[p][col][5 * 32 + aoff]; \
        const bs8 af6 = *(const bs8*)&xh1[p][col][6 * 32 + aoff]; \
        const bs8 af7 = *(const bs8*)&xh1[p][col][7 * 32 + aoff]; \
        f4 a0 = {b1_0, b1_0, b1_0, b1_0}; \
        f4 a1 = {b1_1, b1_1, b1_1, b1_1}; \
        f4 a2 = {b1_2, b1_2, b1_2, b1_2}; \
        f4 a3 = {b1_3, b1_3, b1_3, b1_3}; \
        MFM(a0, af0, w_0_0) MFM(a1, af0, w_1_0) MFM(a2, af0, w_2_0) MFM(a3, af0, w_3_0) \
        MFM(a0, af1, w_0_1) MFM(a1, af1, w_1_1) MFM(a2, af1, w_2_1) MFM(a3, af1, w_3_1) \
        MFM(a0, af2, w_0_2) MFM(a1, af2, w_1_2) MFM(a2, af2, w_2_2) MFM(a3, af2, w_3_2) \
        MFM(a0, af3, w_0_3) MFM(a1, af3, w_1_3) MFM(a2, af3, w_2_3) MFM(a3, af3, w_3_3) \
        MFM(a0, af4, w_0_4) MFM(a1, af4, w_1_4) MFM(a2, af4, w_2_4) MFM(a3, af4, w_3_4) \
        L1WL(0, af5) L1WL(1, af6) L1WL(2, af7) \
        CELLW(a0, a1, a2, a3, 0, HID) CELLW(a0, a1, a2, a3, 1, HID) \
        CELLW(a0, a1, a2, a3, 2, HID) CELLW(a0, a1, a2, a3, 3, HID) }

    // ---- prologue t=0: L0 waves only (h0(-1)=0 from zero-init) ----
    {
        const int p = 0, q = 1;
        if (xldr) xh0[p][xm][xi] = f2bf(xv);
        float xnext = xldr ? xp[INS] : 0.f;
        __syncthreads();
        if (!isL1) L0BODY
        xv = xnext;
    }

    // ---- steady state: L0 waves do time t; L1 waves do time t-1 ----
    for (int t = 1; t < SEQ; ++t) {
        const int p = t & 1, q = p ^ 1;
        if (xldr) xh0[p][xm][xi] = f2bf(xv);
        float xnext = (xldr && (t + 1 < SEQ)) ? xp[(t + 1) * INS] : 0.f;
        __syncthreads();  // x(t), h0(t-1), h1(t-2) visible in parity p

        if (!isL1) L0BODY else L1BODY

        xv = xnext;
    }

    // ---- epilogue: L1 for t = SEQ-1 (SEQ even -> parity 0) ----
    {
        const int p = 0, q = 1;
        __syncthreads();
        if (isL1) L1BODY
    }
    __syncthreads();

    // ---- final FC (128 -> 1) + sigmoid; h1(SEQ-1) in xh1[1][.][HID+..] ----
    if (tid < BC) {
        float s = bfc[0];
#pragma unroll 8
        for (int k2 = 0; k2 < HID; ++k2)
            s += bf2f(xh1[1][tid][HID + k2]) * Wfc[k2];
        out[b0 + tid] = sigm(s);
    }
}

extern "C" void kernel_launch(void* const* d_in, const int* in_sizes, int n_in,
                              void* d_out, int out_size, void* d_ws, size_t ws_size,
                              hipStream_t stream) {
    const float* x    = (const float*)d_in[0];
    const float* Wih0 = (const float*)d_in[1];
    const float* Whh0 = (const float*)d_in[2];
    const float* bih0 = (const float*)d_in[3];
    const float* bhh0 = (const float*)d_in[4];
    const float* Wih1 = (const float*)d_in[5];
    const float* Whh1 = (const float*)d_in[6];
    const float* bih1 = (const float*)d_in[7];
    const float* bhh1 = (const float*)d_in[8];
    const float* Wfc  = (const float*)d_in[9];
    const float* bfc  = (const float*)d_in[10];
    float* out = (float*)d_out;
    short* wsw = (short*)d_ws;   // 426 KB of bf16 fragment-ordered weights

    int nfrag = NFRAG0 + NFRAG1;
    lstm_prep<<<(nfrag + 255) / 256, 256, 0, stream>>>(Wih0, Whh0, bih0, bhh0,
                                                       Wih1, Whh1, wsw);
    dim3 grid(2048 / BC);   // 128 blocks
    dim3 block(1024);       // 16 waves: 8 L0-role + 8 L1-role, 4 waves/SIMD
    lstm_fused<<<grid, block, 0, stream>>>(x, Wfc, bfc, bih1, bhh1, wsw, out);
}

// Round 7
// 961.187 us; speedup vs baseline: 1.5649x; 1.5649x over previous
//
#include <hip/hip_runtime.h>
#include <hip/hip_bf16.h>

#define HID 128
#define SEQ 512
#define INS 14
#define BC 16
// K0 = 160 : [x(14) | 1 | pad->32 | h0(128)]   -> 5 k-steps of 32
// K1 = 256 : [h0(128) | h1(128)]               -> 8 k-steps of 32
#define X0STRIDE 40
#define X1STRIDE 264  // 256 + 8 pad shorts; row stride 132 dw = 4 mod 32 -> 2-way reads (free)
#define NFRAG0 10240          // 8 waves * 4 gates * 5 ksteps * 64 lanes
#define NFRAG1 16384          // 8 waves * 4 gates * 8 ksteps * 64 lanes
#define W1BASE (NFRAG0 * 8)   // short offset of W1 region in ws

typedef __attribute__((ext_vector_type(8))) short bs8;
typedef __attribute__((ext_vector_type(4))) float f4;

__device__ __forceinline__ short f2bf(float f) {
    union { float f; unsigned u; } a; a.f = f;
    unsigned u = a.u;
    u += 0x7fffu + ((u >> 16) & 1u);   // RNE
    return (short)(u >> 16);
}
__device__ __forceinline__ float bf2f(short s) {
    union { unsigned u; float f; } a;
    a.u = ((unsigned)(unsigned short)s) << 16;
    return a.f;
}
__device__ __forceinline__ float sigm(float x) {
    return __builtin_amdgcn_rcpf(1.f + __builtin_amdgcn_exp2f(x * -1.44269504f));
}

// ---------------------------------------------------------------------------
// prep: swizzle weights into MFMA B-fragment order in ws (bf16 bits).
// ---------------------------------------------------------------------------
__global__ void lstm_prep(
    const float* __restrict__ Wih0, const float* __restrict__ Whh0,
    const float* __restrict__ bih0, const float* __restrict__ bhh0,
    const float* __restrict__ Wih1, const float* __restrict__ Whh1,
    short* __restrict__ wsw)
{
    int f = blockIdx.x * 256 + threadIdx.x;
    if (f >= NFRAG0 + NFRAG1) return;
    if (f < NFRAG0) {
        int lane = f & 63, t = f >> 6;
        int ks = t % 5, gw = t / 5, g = gw & 3, wv = gw >> 2;
        int row = g * HID + wv * 16 + (lane & 15);
        int kbase = ks * 32 + (lane >> 4) * 8;
        for (int j = 0; j < 8; ++j) {
            int k = kbase + j;
            float v;
            if (k < INS)        v = Wih0[row * INS + k];
            else if (k == INS)  v = bih0[row] + bhh0[row];
            else if (k < 32)    v = 0.f;
            else                v = Whh0[row * HID + (k - 32)];
            wsw[f * 8 + j] = f2bf(v);
        }
    } else {
        int fl = f - NFRAG0;
        int lane = fl & 63, t = fl >> 6;
        int ks = t & 7, g = (t >> 3) & 3, wv = t >> 5;
        int row = g * HID + wv * 16 + (lane & 15);
        int kbase = ks * 32 + (lane >> 4) * 8;
        for (int j = 0; j < 8; ++j) {
            int k = kbase + j;
            float v = (k < HID) ? Wih1[row * HID + k] : Whh1[row * HID + (k - HID)];
            wsw[f * 8 + j] = f2bf(v);
        }
    }
}

// ---------------------------------------------------------------------------
// main. Round-7 = round-4 structure (best verified, 977 us) + two issue-cycle
// reductions, no liveness change:
//  (a) h-store packing via v_cvt_pk_bf16_f32 (hw RNE): per row-pair 1 cvt +
//      1 shr + 2 ds_write_b16 replaces 2 manual-RNE f2bf (8 VALU) + 2 writes.
//  (b) x-loader rebalance: 2 batch rows per wave (28 active lanes/wave)
//      instead of 224 loaders packed into waves 0-3 -> removes the wave-0-3
//      staging tail all 8 waves waited out at the barrier.
// r5 (wave de-phase) and r6 (role-split, 4 waves/SIMD) both regressed:
// weights (416 KB/CU) pin the design to 2 waves/SIMD + 150 KB LDS; occupancy
// cannot rise without spills (r6 canary: WRITE_SIZE 8 KB -> 8.2 MB).
// Spill canary: WRITE_SIZE (~8 KB @ r4).
// ---------------------------------------------------------------------------
__global__ __attribute__((amdgpu_flat_work_group_size(512, 512)))
__attribute__((amdgpu_waves_per_eu(2, 2))) void lstm_fused(
    const float* __restrict__ x,
    const float* __restrict__ Wfc,  const float* __restrict__ bfc,
    const float* __restrict__ bih1, const float* __restrict__ bhh1,
    const short* __restrict__ wsw,
    float* __restrict__ out)
{
    __shared__ __align__(16) short xh0[2][BC][X0STRIDE];
    __shared__ __align__(16) short xh1[2][BC][X1STRIDE];
    // L1 ks4-7 weights: [wv][ks-4][gate][lane][8] -> 128 KB, per-wave private
    __shared__ __align__(16) short wlds[8][4][4][64][8];

    const int tid  = threadIdx.x;
    const int lane = tid & 63;
    const int wv   = tid >> 6;      // 0..7
    const int col  = lane & 15;
    const int quad = lane >> 4;
    const int u    = wv * 16 + col; // hidden unit owned by this lane
    const int b0   = blockIdx.x * BC;

    // ---- register-resident weight fragments: L0 all 20, L1 ks0-3 (16) ----
    const short* wb0 = wsw + ((wv * 20) * 64 + lane) * 8;           // wv*4*5
    const short* wb1 = wsw + W1BASE + ((wv * 32) * 64 + lane) * 8;  // wv*4*8
#define DW0(g,ks) const bs8 w0_##g##_##ks = *(const bs8*)(wb0 + ((g)*5+(ks))*512);
#define DW1(g,ks) const bs8 w1_##g##_##ks = *(const bs8*)(wb1 + ((g)*8+(ks))*512);
    DW0(0,0) DW0(0,1) DW0(0,2) DW0(0,3) DW0(0,4)
    DW0(1,0) DW0(1,1) DW0(1,2) DW0(1,3) DW0(1,4)
    DW0(2,0) DW0(2,1) DW0(2,2) DW0(2,3) DW0(2,4)
    DW0(3,0) DW0(3,1) DW0(3,2) DW0(3,3) DW0(3,4)
    DW1(0,0) DW1(0,1) DW1(0,2) DW1(0,3)
    DW1(1,0) DW1(1,1) DW1(1,2) DW1(1,3)
    DW1(2,0) DW1(2,1) DW1(2,2) DW1(2,3)
    DW1(3,0) DW1(3,1) DW1(3,2) DW1(3,3)

    const float b1_0 = bih1[0 * HID + u] + bhh1[0 * HID + u];
    const float b1_1 = bih1[1 * HID + u] + bhh1[1 * HID + u];
    const float b1_2 = bih1[2 * HID + u] + bhh1[2 * HID + u];
    const float b1_3 = bih1[3 * HID + u] + bhh1[3 * HID + u];

    // ---- LDS init: zeros + constant-1 bias column + L1 ks4-7 weight tiles ----
    for (int idx = tid; idx < 2 * BC * X0STRIDE; idx += 512) ((short*)xh0)[idx] = 0;
    for (int idx = tid; idx < 2 * BC * X1STRIDE; idx += 512) ((short*)xh1)[idx] = 0;
#pragma unroll
    for (int f = 0; f < 16; ++f) {
        int ksm4 = f >> 2, g = f & 3;
        *(bs8*)&wlds[wv][ksm4][g][lane][0] =
            *(const bs8*)(wsw + W1BASE +
                (((wv * 4 + g) * 8 + (ksm4 + 4)) * 64 + lane) * 8);
    }
    __syncthreads();
    if (tid < 2 * BC) xh0[tid >> 4][tid & 15][INS] = (short)0x3f80;  // 1.0 bf16

    // ---- x(t) staging: 2 batch rows per wave, 28 active lanes per wave ----
    const int  xm = wv * 2 + (lane >> 5);   // batch row 0..15
    const int  xi = lane & 31;              // input feature
    const bool xldr = (xi < INS);
    const float* xp = xldr ? (x + ((size_t)(b0 + xm) * SEQ) * INS + xi) : x;
    float xv = xldr ? xp[0] : 0.f;

    float c0_0 = 0.f, c0_1 = 0.f, c0_2 = 0.f, c0_3 = 0.f;
    float c1_0 = 0.f, c1_1 = 0.f, c1_2 = 0.f, c1_3 = 0.f;
    const int aoff = quad * 8;

    // ---- MFMA macros; AF passed explicitly (af temps shared L1<->L0) ----
#define L1KR(ks, AF) { \
        acc1_0 = __builtin_amdgcn_mfma_f32_16x16x32_bf16(AF, w1_0_##ks, acc1_0, 0,0,0); \
        acc1_1 = __builtin_amdgcn_mfma_f32_16x16x32_bf16(AF, w1_1_##ks, acc1_1, 0,0,0); \
        acc1_2 = __builtin_amdgcn_mfma_f32_16x16x32_bf16(AF, w1_2_##ks, acc1_2, 0,0,0); \
        acc1_3 = __builtin_amdgcn_mfma_f32_16x16x32_bf16(AF, w1_3_##ks, acc1_3, 0,0,0); }
#define L1KL(ks, AF) { \
        const bs8 u0 = *(const bs8*)&wlds[wv][(ks)-4][0][lane][0]; \
        const bs8 u1 = *(const bs8*)&wlds[wv][(ks)-4][1][lane][0]; \
        const bs8 u2 = *(const bs8*)&wlds[wv][(ks)-4][2][lane][0]; \
        const bs8 u3 = *(const bs8*)&wlds[wv][(ks)-4][3][lane][0]; \
        acc1_0 = __builtin_amdgcn_mfma_f32_16x16x32_bf16(AF, u0, acc1_0, 0,0,0); \
        acc1_1 = __builtin_amdgcn_mfma_f32_16x16x32_bf16(AF, u1, acc1_1, 0,0,0); \
        acc1_2 = __builtin_amdgcn_mfma_f32_16x16x32_bf16(AF, u2, acc1_2, 0,0,0); \
        acc1_3 = __builtin_amdgcn_mfma_f32_16x16x32_bf16(AF, u3, acc1_3, 0,0,0); }
#define L0K(ks, AF) { \
        acc0_0 = __builtin_amdgcn_mfma_f32_16x16x32_bf16(AF, w0_0_##ks, acc0_0, 0,0,0); \
        acc0_1 = __builtin_amdgcn_mfma_f32_16x16x32_bf16(AF, w0_1_##ks, acc0_1, 0,0,0); \
        acc0_2 = __builtin_amdgcn_mfma_f32_16x16x32_bf16(AF, w0_2_##ks, acc0_2, 0,0,0); \
        acc0_3 = __builtin_amdgcn_mfma_f32_16x16x32_bf16(AF, w0_3_##ks, acc0_3, 0,0,0); }

    // ---- merged-denominator LSTM cell: 5 exp2 + 2 rcp per row -> h value ----
#define CELLH(A0, A1, A2, A3, cvar, r, HOUT) { \
        float ei = __builtin_amdgcn_exp2f(A0[r] * -1.44269504f); \
        float ef = __builtin_amdgcn_exp2f(A1[r] * -1.44269504f); \
        float eg = __builtin_amdgcn_exp2f(A2[r] * -2.88539008f); \
        float eo = __builtin_amdgcn_exp2f(A3[r] * -1.44269504f); \
        float Di = 1.f + ei, Df = 1.f + ef, Dg = 1.f + eg, Do = 1.f + eo; \
        float rP = __builtin_amdgcn_rcpf(Df * Di * Dg); \
        float num = __builtin_fmaf(cvar * Di, Dg, (1.f - eg) * Df); \
        cvar = num * rP; \
        float ec = __builtin_amdgcn_exp2f(cvar * -2.88539008f); \
        float rQ = __builtin_amdgcn_rcpf((1.f + ec) * Do); \
        HOUT = (1.f - ec) * rQ; }

    // pack 2 h values (rows 2j, 2j+1 of this quad) with hw RNE, 2 b16 stores
#define STOREPAIR(HA, HB, J, ROW, COLOFF) { \
        unsigned pk; \
        asm("v_cvt_pk_bf16_f32 %0, %1, %2" : "=v"(pk) : "v"(HA), "v"(HB)); \
        xh1[ROW][quad * 4 + 2*(J)][(COLOFF) + u]     = (short)pk; \
        xh1[ROW][quad * 4 + 2*(J) + 1][(COLOFF) + u] = (short)(pk >> 16); }

#define CELL4_0(ROW) { \
        float h0_, h1_, h2_, h3_; \
        CELLH(acc0_0, acc0_1, acc0_2, acc0_3, c0_0, 0, h0_) \
        CELLH(acc0_0, acc0_1, acc0_2, acc0_3, c0_1, 1, h1_) \
        CELLH(acc0_0, acc0_1, acc0_2, acc0_3, c0_2, 2, h2_) \
        CELLH(acc0_0, acc0_1, acc0_2, acc0_3, c0_3, 3, h3_) \
        STOREPAIR(h0_, h1_, 0, ROW, 0) STOREPAIR(h2_, h3_, 1, ROW, 0) }

#define CELL1H(r, HOUT) CELLH(acc1_0, acc1_1, acc1_2, acc1_3, c1_##r, r, HOUT)

    // ---- prologue t=0: layer 0 only (h0(-1)=0 from zero-init) ----
    {
        const int p = 0, q = 1;
        if (xldr) xh0[p][xm][xi] = f2bf(xv);
        float xnext = xldr ? xp[INS] : 0.f;
        __syncthreads();
        const bs8 afx = *(const bs8*)&xh0[p][col][aoff];
        const bs8 af0 = *(const bs8*)&xh1[p][col][0 * 32 + aoff];
        const bs8 af1 = *(const bs8*)&xh1[p][col][1 * 32 + aoff];
        const bs8 af2 = *(const bs8*)&xh1[p][col][2 * 32 + aoff];
        const bs8 af3 = *(const bs8*)&xh1[p][col][3 * 32 + aoff];
        f4 acc0_0 = {0.f,0.f,0.f,0.f}, acc0_1 = {0.f,0.f,0.f,0.f};
        f4 acc0_2 = {0.f,0.f,0.f,0.f}, acc0_3 = {0.f,0.f,0.f,0.f};
        L0K(0, afx) L0K(1, af0) L0K(2, af1) L0K(3, af2) L0K(4, af3)
        CELL4_0(q)
        xv = xnext;
    }

    // ---- steady state: iter t does L1/CELL1 for t-1 and L0/CELL0 for t ----
    for (int t = 1; t < SEQ; ++t) {
        const int p = t & 1, q = p ^ 1;
        if (xldr) xh0[p][xm][xi] = f2bf(xv);
        float xnext = (xldr && (t + 1 < SEQ)) ? xp[(t + 1) * INS] : 0.f;
        __syncthreads();  // x(t), h0(t-1), h1(t-2) all visible in parity p

        // A-row burst: 9 ds_read_b128, loaded once, shared by L1 and L0
        const bs8 afx = *(const bs8*)&xh0[p][col][aoff];
        const bs8 af0 = *(const bs8*)&xh1[p][col][0 * 32 + aoff];
        const bs8 af1 = *(const bs8*)&xh1[p][col][1 * 32 + aoff];
        const bs8 af2 = *(const bs8*)&xh1[p][col][2 * 32 + aoff];
        const bs8 af3 = *(const bs8*)&xh1[p][col][3 * 32 + aoff];
        const bs8 af4 = *(const bs8*)&xh1[p][col][4 * 32 + aoff];
        const bs8 af5 = *(const bs8*)&xh1[p][col][5 * 32 + aoff];
        const bs8 af6 = *(const bs8*)&xh1[p][col][6 * 32 + aoff];
        const bs8 af7 = *(const bs8*)&xh1[p][col][7 * 32 + aoff];

        f4 acc1_0 = {b1_0, b1_0, b1_0, b1_0};
        f4 acc1_1 = {b1_1, b1_1, b1_1, b1_1};
        f4 acc1_2 = {b1_2, b1_2, b1_2, b1_2};
        f4 acc1_3 = {b1_3, b1_3, b1_3, b1_3};
        L1KR(0, af0) L1KR(1, af1) L1KR(2, af2) L1KR(3, af3)
        L1KL(4, af4) L1KL(5, af5) L1KL(6, af6) L1KL(7, af7)

        f4 acc0_0 = {0.f,0.f,0.f,0.f}, acc0_1 = {0.f,0.f,0.f,0.f};
        f4 acc0_2 = {0.f,0.f,0.f,0.f}, acc0_3 = {0.f,0.f,0.f,0.f};
        // interleave: matrix pipe (L0) and trans pipe (CELL1) concurrently
        float g0_, g1_, g2_, g3_;
        L0K(0, afx) CELL1H(0, g0_)
        L0K(1, af0) CELL1H(1, g1_)
        L0K(2, af1) CELL1H(2, g2_)
        L0K(3, af2) CELL1H(3, g3_)
        L0K(4, af3)
        STOREPAIR(g0_, g1_, 0, q, HID) STOREPAIR(g2_, g3_, 1, q, HID)
        CELL4_0(q)

        xv = xnext;
    }

    // ---- epilogue: L1/CELL1 for t = SEQ-1 (SEQ even -> parity 0) ----
    {
        const int p = 0, q = 1;
        __syncthreads();
        const bs8 af0 = *(const bs8*)&xh1[p][col][0 * 32 + aoff];
        const bs8 af1 = *(const bs8*)&xh1[p][col][1 * 32 + aoff];
        const bs8 af2 = *(const bs8*)&xh1[p][col][2 * 32 + aoff];
        const bs8 af3 = *(const bs8*)&xh1[p][col][3 * 32 + aoff];
        const bs8 af4 = *(const bs8*)&xh1[p][col][4 * 32 + aoff];
        const bs8 af5 = *(const bs8*)&xh1[p][col][5 * 32 + aoff];
        const bs8 af6 = *(const bs8*)&xh1[p][col][6 * 32 + aoff];
        const bs8 af7 = *(const bs8*)&xh1[p][col][7 * 32 + aoff];
        f4 acc1_0 = {b1_0, b1_0, b1_0, b1_0};
        f4 acc1_1 = {b1_1, b1_1, b1_1, b1_1};
        f4 acc1_2 = {b1_2, b1_2, b1_2, b1_2};
        f4 acc1_3 = {b1_3, b1_3, b1_3, b1_3};
        L1KR(0, af0) L1KR(1, af1) L1KR(2, af2) L1KR(3, af3)
        L1KL(4, af4) L1KL(5, af5) L1KL(6, af6) L1KL(7, af7)
        float g0_, g1_, g2_, g3_;
        CELL1H(0, g0_) CELL1H(1, g1_) CELL1H(2, g2_) CELL1H(3, g3_)
        STOREPAIR(g0_, g1_, 0, q, HID) STOREPAIR(g2_, g3_, 1, q, HID)
    }
    __syncthreads();

    // ---- final FC (128 -> 1) + sigmoid; h1(SEQ-1) lives in xh1[1][.][HID+..] ----
    if (tid < BC) {
        float s = bfc[0];
#pragma unroll 8
        for (int k2 = 0; k2 < HID; ++k2)
            s += bf2f(xh1[1][tid][HID + k2]) * Wfc[k2];
        out[b0 + tid] = sigm(s);
    }
}

extern "C" void kernel_launch(void* const* d_in, const int* in_sizes, int n_in,
                              void* d_out, int out_size, void* d_ws, size_t ws_size,
                              hipStream_t stream) {
    const float* x    = (const float*)d_in[0];
    const float* Wih0 = (const float*)d_in[1];
    const float* Whh0 = (const float*)d_in[2];
    const float* bih0 = (const float*)d_in[3];
    const float* bhh0 = (const float*)d_in[4];
    const float* Wih1 = (const float*)d_in[5];
    const float* Whh1 = (const float*)d_in[6];
    const float* bih1 = (const float*)d_in[7];
    const float* bhh1 = (const float*)d_in[8];
    const float* Wfc  = (const float*)d_in[9];
    const float* bfc  = (const float*)d_in[10];
    float* out = (float*)d_out;
    short* wsw = (short*)d_ws;   // 426 KB of bf16 fragment-ordered weights

    int nfrag = NFRAG0 + NFRAG1;
    lstm_prep<<<(nfrag + 255) / 256, 256, 0, stream>>>(Wih0, Whh0, bih0, bhh0,
                                                       Wih1, Whh1, wsw);
    dim3 grid(2048 / BC);   // 128 blocks, 1 per CU
    dim3 block(512);        // 8 waves; each wave owns 16 hidden units
    lstm_fused<<<grid, block, 0, stream>>>(x, Wfc, bfc, bih1, bhh1, wsw, out);
}